// Round 9
// baseline (249.810 us; speedup 1.0000x reference)
//
#include <hip/hip_runtime.h>
#include <math.h>
#include <float.h>

#define D 256
#define K 1024
#define NROWS 32768
#define NBLK (NROWS / 32)      // 1024 blocks, M=32 rows each
#define MARGIN 1.0f            // z-margin for np-replica near-tie refinement
#define MAXCAND 12

#define LOSS_OFF 8388608
#define IDX_OFF  8388609

typedef _Float16 h8 __attribute__((ext_vector_type(8)));
typedef float    v4f __attribute__((ext_vector_type(4)));

// ---- numpy pairwise sum replica for sum(a*a) over 128 contiguous floats ----
__device__ __forceinline__ float np_sq_block128(const float* a) {
    float r0 = __fmul_rn(a[0], a[0]);
    float r1 = __fmul_rn(a[1], a[1]);
    float r2 = __fmul_rn(a[2], a[2]);
    float r3 = __fmul_rn(a[3], a[3]);
    float r4 = __fmul_rn(a[4], a[4]);
    float r5 = __fmul_rn(a[5], a[5]);
    float r6 = __fmul_rn(a[6], a[6]);
    float r7 = __fmul_rn(a[7], a[7]);
    for (int i = 8; i < 128; i += 8) {
        r0 = __fadd_rn(r0, __fmul_rn(a[i + 0], a[i + 0]));
        r1 = __fadd_rn(r1, __fmul_rn(a[i + 1], a[i + 1]));
        r2 = __fadd_rn(r2, __fmul_rn(a[i + 2], a[i + 2]));
        r3 = __fadd_rn(r3, __fmul_rn(a[i + 3], a[i + 3]));
        r4 = __fadd_rn(r4, __fmul_rn(a[i + 4], a[i + 4]));
        r5 = __fadd_rn(r5, __fmul_rn(a[i + 5], a[i + 5]));
        r6 = __fadd_rn(r6, __fmul_rn(a[i + 6], a[i + 6]));
        r7 = __fadd_rn(r7, __fmul_rn(a[i + 7], a[i + 7]));
    }
    float tA = __fadd_rn(__fadd_rn(r0, r1), __fadd_rn(r2, r3));
    float tB = __fadd_rn(__fadd_rn(r4, r5), __fadd_rn(r6, r7));
    return __fadd_rn(tA, tB);
}

// ---- fused prep: fragment convert + coalesced numpy-exact b2 + ws zero -----
// cfrag[(s*64 + T)*64 + qd*16 + ln] = f16x8 of code (T*16+ln), dims s*32+qd*8..+7
// b2 via wave-per-4-codes: lane (j=l&7, half=(l>>3)&1) computes numpy's r_j
// serially; shfl_xor 1/2/4 rebuilds ((r0+r1)+(r2+r3))+((r4+r5)+(r6+r7));
// shfl_xor 8 adds blockA+blockB. Exact numpy pairwise order (commutative ops).
__global__ void vq_prep(const float* __restrict__ cb, float* __restrict__ b2,
                        h8* __restrict__ cfrag, float* __restrict__ avg_acc,
                        float* __restrict__ scal) {
    int tid = blockIdx.x * 256 + threadIdx.x;      // 0..32767
    {   // fragment-ordered fp16 convert (coalesced 16B writes)
        int ln = tid & 15;
        int qd = (tid >> 4) & 3;
        int T  = (tid >> 6) & 63;
        int s  = tid >> 12;
        int k  = T * 16 + ln;
        const float* c = cb + (size_t)k * D + s * 32 + qd * 8;
        float4 v0 = *(const float4*)c;
        float4 v1 = *(const float4*)(c + 4);
        h8 f;
        f[0] = (_Float16)v0.x; f[1] = (_Float16)v0.y;
        f[2] = (_Float16)v0.z; f[3] = (_Float16)v0.w;
        f[4] = (_Float16)v1.x; f[5] = (_Float16)v1.y;
        f[6] = (_Float16)v1.z; f[7] = (_Float16)v1.w;
        cfrag[tid] = f;
    }
    // coalesced numpy-exact b2 (first 256 waves; 4 codes per wave)
    int gw = tid >> 6;
    if (gw < 256) {
        int l    = tid & 63;
        int code = gw * 4 + (l >> 4);
        int j    = l & 7;
        int half = (l >> 3) & 1;
        const float* c = cb + (size_t)code * D + half * 128 + j;
        float v = __fmul_rn(c[0], c[0]);
        #pragma unroll
        for (int m = 1; m < 16; ++m)
            v = __fadd_rn(v, __fmul_rn(c[8 * m], c[8 * m]));
        v = __fadd_rn(v, __shfl_xor(v, 1));
        v = __fadd_rn(v, __shfl_xor(v, 2));
        v = __fadd_rn(v, __shfl_xor(v, 4));
        v = __fadd_rn(v, __shfl_xor(v, 8));
        if ((l & 15) == 0) b2[code] = v;
    }
    // zero accumulators (kernel-order guarantees visibility before vq_mfma)
    if (tid >= 1024 && tid < 2048) avg_acc[tid - 1024] = 0.f;
    if (tid >= 2048 && tid < 2051) scal[tid - 2048] = 0.f;   // mse, H, counter
}

// ---- fused MFMA GEMM + argmin + softmax stats + outputs + last-block loss --
// 512 thr = 8 waves; wave w: codes [128w,128w+128) x 32 rows. B double-buffered
// in VGPRs (compiler emits fine-grained vmcnt); A register-resident fp16.
__global__ __launch_bounds__(512, 2)
void vq_mfma(const float* __restrict__ x, const float* __restrict__ cb,
             const h8* __restrict__ cfrag, const float* __restrict__ b2,
             float* __restrict__ avg_acc, float* __restrict__ scal,
             float* __restrict__ out)
{
    __shared__ float mred[8][32];
    __shared__ int   kred[8][32];
    __shared__ float sred[8][32];
    __shared__ float tred[8][32];
    __shared__ int   bkl[32];
    __shared__ int   candn[32];
    __shared__ int   candk[32][MAXCAND];
    __shared__ __align__(16) float xbuf[256];
    __shared__ int   lastflag;
    __shared__ float finred[8];

    const int t   = threadIdx.x;
    const int w   = t >> 6;        // wave = code-group q (0..7), N=128 each
    const int q   = w;
    const int l64 = t & 63;
    const int qd  = l64 >> 4;      // k-chunk (A/B) / row-subgroup (C)
    const int ln  = l64 & 15;      // m (A) / n (B) / col (C)
    const int r0  = blockIdx.x * 32;

    if (t < 32) candn[t] = 0;

    // ---- A register-resident: 2 M-tiles x 8 k-steps of fp16 frags ----
    h8 afr[2][8];
    #pragma unroll
    for (int m = 0; m < 2; ++m) {
        const float* xr = x + (size_t)(r0 + 16 * m + ln) * D + qd * 8;
        #pragma unroll
        for (int s = 0; s < 8; ++s) {
            float4 a0 = *(const float4*)(xr + 32 * s);
            float4 a1 = *(const float4*)(xr + 32 * s + 4);
            h8 f;
            f[0] = (_Float16)a0.x; f[1] = (_Float16)a0.y;
            f[2] = (_Float16)a0.z; f[3] = (_Float16)a0.w;
            f[4] = (_Float16)a1.x; f[5] = (_Float16)a1.y;
            f[6] = (_Float16)a1.z; f[7] = (_Float16)a1.w;
            afr[m][s] = f;
        }
    }

    v4f acc[2][8];                 // [M-tile][N-tile]
    #pragma unroll
    for (int rt = 0; rt < 2; ++rt)
        #pragma unroll
        for (int tt = 0; tt < 8; ++tt) acc[rt][tt] = (v4f)0.f;

    // ---- K-loop: B double-buffered in VGPRs, no LDS, no barriers ----
    const h8* bp = cfrag + (size_t)(8 * w) * 64 + l64;   // + s*4096 + tt*64
    h8 bb[2][8];
    #pragma unroll
    for (int tt = 0; tt < 8; ++tt) bb[0][tt] = bp[tt * 64];          // s=0
    #pragma unroll
    for (int s = 0; s < 8; ++s) {
        const int cur = s & 1, nxt = cur ^ 1;
        if (s < 7) {
            #pragma unroll
            for (int tt = 0; tt < 8; ++tt)
                bb[nxt][tt] = bp[(s + 1) * 4096 + tt * 64];          // prefetch
        }
        #pragma unroll
        for (int tt = 0; tt < 8; ++tt) {
            acc[0][tt] = __builtin_amdgcn_mfma_f32_16x16x32_f16(afr[0][s], bb[cur][tt], acc[0][tt], 0, 0, 0);
            acc[1][tt] = __builtin_amdgcn_mfma_f32_16x16x32_f16(afr[1][s], bb[cur][tt], acc[1][tt], 0, 0, 0);
        }
    }

    // ---- z = 200*dot - 100*||c||^2 ----
    float b2c[8];
    #pragma unroll
    for (int tt = 0; tt < 8; ++tt) b2c[tt] = b2[128 * q + 16 * tt + ln];
    #pragma unroll
    for (int rt = 0; rt < 2; ++rt)
        #pragma unroll
        for (int tt = 0; tt < 8; ++tt)
            #pragma unroll
            for (int r = 0; r < 4; ++r)
                acc[rt][tt][r] = 200.f * acc[rt][tt][r] - 100.f * b2c[tt];

    // ---- per-row local max over this wave's 16 cols ----
    float m[2][4]; int bk[2][4];
    #pragma unroll
    for (int rt = 0; rt < 2; ++rt)
        #pragma unroll
        for (int r = 0; r < 4; ++r) { m[rt][r] = -INFINITY; bk[rt][r] = K; }
    #pragma unroll
    for (int tt = 0; tt < 8; ++tt)
        #pragma unroll
        for (int rt = 0; rt < 2; ++rt)
            #pragma unroll
            for (int r = 0; r < 4; ++r) {
                float z = acc[rt][tt][r];
                int code = 128 * q + 16 * tt + ln;
                if (z > m[rt][r]) { m[rt][r] = z; bk[rt][r] = code; }
            }
    #pragma unroll
    for (int off = 1; off < 16; off <<= 1)
        #pragma unroll
        for (int rt = 0; rt < 2; ++rt)
            #pragma unroll
            for (int r = 0; r < 4; ++r) {
                float om = __shfl_xor(m[rt][r], off);
                int   ok = __shfl_xor(bk[rt][r], off);
                if (om > m[rt][r] || (om == m[rt][r] && ok < bk[rt][r])) {
                    m[rt][r] = om; bk[rt][r] = ok;
                }
            }
    if (ln == 0)
        #pragma unroll
        for (int rt = 0; rt < 2; ++rt)
            #pragma unroll
            for (int r = 0; r < 4; ++r) {
                int rl = 16 * rt + 4 * qd + r;
                mred[q][rl] = m[rt][r]; kred[q][rl] = bk[rt][r];
            }
    __syncthreads();

    // ---- combine groups (codes ascend with q -> '>' keeps low idx) ----
    float mf[2][4]; int kf[2][4];
    #pragma unroll
    for (int rt = 0; rt < 2; ++rt)
        #pragma unroll
        for (int r = 0; r < 4; ++r) {
            int rl = 16 * rt + 4 * qd + r;
            mf[rt][r] = mred[0][rl]; kf[rt][r] = kred[0][rl];
            #pragma unroll
            for (int qq = 1; qq < 8; ++qq) {
                float mm = mred[qq][rl];
                if (mm > mf[rt][r]) { mf[rt][r] = mm; kf[rt][r] = kred[qq][rl]; }
            }
        }

    // ---- S,T with global max; candidate append; stash e-values ----
    float S[2][4] = {{0,0,0,0},{0,0,0,0}}, T[2][4] = {{0,0,0,0},{0,0,0,0}};
    #pragma unroll
    for (int tt = 0; tt < 8; ++tt)
        #pragma unroll
        for (int rt = 0; rt < 2; ++rt)
            #pragma unroll
            for (int r = 0; r < 4; ++r) {
                float z  = acc[rt][tt][r];
                float zz = z - mf[rt][r];
                float e  = __expf(zz);
                if (z > mf[rt][r] - MARGIN) {
                    int rl = 16 * rt + 4 * qd + r;
                    int slot = atomicAdd(&candn[rl], 1);
                    if (slot < MAXCAND) candk[rl][slot] = 128 * q + 16 * tt + ln;
                }
                S[rt][r] += e; T[rt][r] += zz * e;
                acc[rt][tt][r] = e;
            }
    #pragma unroll
    for (int off = 1; off < 16; off <<= 1)
        #pragma unroll
        for (int rt = 0; rt < 2; ++rt)
            #pragma unroll
            for (int r = 0; r < 4; ++r) {
                S[rt][r] += __shfl_xor(S[rt][r], off);
                T[rt][r] += __shfl_xor(T[rt][r], off);
            }
    if (ln == 0)
        #pragma unroll
        for (int rt = 0; rt < 2; ++rt)
            #pragma unroll
            for (int r = 0; r < 4; ++r) {
                int rl = 16 * rt + 4 * qd + r;
                sred[q][rl] = S[rt][r]; tred[q][rl] = T[rt][r];
            }
    __syncthreads();

    float iS[2][4];
    float hsum = 0.f;
    #pragma unroll
    for (int rt = 0; rt < 2; ++rt)
        #pragma unroll
        for (int r = 0; r < 4; ++r) {
            int rl = 16 * rt + 4 * qd + r;
            float Sf = 0.f, Tf = 0.f;
            #pragma unroll
            for (int qq = 0; qq < 8; ++qq) { Sf += sred[qq][rl]; Tf += tred[qq][rl]; }
            iS[rt][r] = 1.f / Sf;
            if (q == 0 && ln == 0) {
                bkl[rl] = kf[rt][r];
                hsum += Tf * iS[rt][r] - __logf(Sf);
            }
        }
    if (q == 0 && ln == 0) atomicAdd(&scal[1], hsum);

    // ---- sparse avg_probs emission ----
    #pragma unroll
    for (int tt = 0; tt < 8; ++tt)
        #pragma unroll
        for (int rt = 0; rt < 2; ++rt)
            #pragma unroll
            for (int r = 0; r < 4; ++r) {
                float p = acc[rt][tt][r] * iS[rt][r];
                if (p > 1e-12f)
                    atomicAdd(&avg_acc[128 * q + 16 * tt + ln], p);
            }
    __syncthreads();

    // ---- near-tie slow path (wave 0): numpy fp32-pipeline replica ----
    if (w == 0) {
        for (int row = 0; row < 32; ++row) {
            int tc = candn[row];
            if (tc < 2) continue;
            if (tc > MAXCAND) tc = MAXCAND;
            const float* xr = x + (size_t)(r0 + row) * D;
            *(float4*)&xbuf[l64 * 4] = *(const float4*)(xr + l64 * 4);
            float a2f = __fadd_rn(np_sq_block128(xbuf), np_sq_block128(xbuf + 128));
            float bestd = FLT_MAX; int bestk = K;
            for (int c = 0; c < tc; ++c) {
                int k = candk[row][c];
                double sdot = 0.0;
                #pragma unroll
                for (int dd = 0; dd < 4; ++dd)
                    sdot += (double)cb[(size_t)k * D + l64 * 4 + dd] *
                            (double)xbuf[l64 * 4 + dd];
                #pragma unroll
                for (int off = 32; off > 0; off >>= 1)
                    sdot += __shfl_xor(sdot, off);
                float abf = (float)sdot;
                float dnp = __fsub_rn(__fadd_rn(a2f, b2[k]), __fmul_rn(2.0f, abf));
                if (dnp < bestd || (dnp == bestd && k < bestk)) {
                    bestd = dnp; bestk = k;
                }
            }
            if (l64 == 0) bkl[row] = bestk;
        }
    }
    __syncthreads();

    // ---- outputs: wave w -> rows 4w..4w+3 ----
    float wmse = 0.f;
    #pragma unroll
    for (int rr = 0; rr < 4; ++rr) {
        int rl  = 4 * w + rr;
        int row = r0 + rl;
        int bk2 = bkl[rl];
        float4 xv = *(const float4*)(x  + (size_t)row * D + l64 * 4);
        float4 qv = *(const float4*)(cb + (size_t)bk2 * D + l64 * 4);
        float dx = qv.x - xv.x, dy = qv.y - xv.y, dz = qv.z - xv.z, dw = qv.w - xv.w;
        float4 st;
        st.x = xv.x + dx; st.y = xv.y + dy; st.z = xv.z + dz; st.w = xv.w + dw;
        *(float4*)(out + (size_t)row * D + l64 * 4) = st;
        if (l64 == 0) out[IDX_OFF + row] = (float)bk2;
        wmse += dx * dx + dy * dy + dz * dz + dw * dw;
    }
    #pragma unroll
    for (int off = 32; off > 0; off >>= 1)
        wmse += __shfl_xor(wmse, off);
    if (l64 == 0) atomicAdd(&scal[0], wmse);

    // ---- last block finalizes the loss (fused vq_fin) ----
    __syncthreads();               // drains vmcnt: all our atomics complete
    if (t == 0) {
        unsigned prev = atomicAdd((unsigned*)(scal + 2), 1u);
        lastflag = (prev == NBLK - 1) ? 1 : 0;
    }
    __syncthreads();
    if (lastflag) {
        float v = 0.f;
        #pragma unroll
        for (int h = 0; h < 2; ++h) {
            int i = t + 512 * h;
            float ap = atomicAdd(&avg_acc[i], 0.0f) * (1.f / 32768.f);
            v += ap * logf(ap + 1e-5f);
        }
        #pragma unroll
        for (int off = 32; off > 0; off >>= 1) v += __shfl_xor(v, off);
        if (l64 == 0) finred[w] = v;
        __syncthreads();
        if (t == 0) {
            float s = 0.f;
            for (int ww = 0; ww < 8; ++ww) s += finred[ww];
            float avg_entropy = -s;
            float sampleH = -atomicAdd(&scal[1], 0.0f) * (1.f / 32768.f);
            float mse = atomicAdd(&scal[0], 0.0f) * (1.f / 8388608.f);
            out[LOSS_OFF] = 1.25f * mse + 0.1f * (sampleH - avg_entropy);
        }
    }
}

extern "C" void kernel_launch(void* const* d_in, const int* in_sizes, int n_in,
                              void* d_out, int out_size, void* d_ws, size_t ws_size,
                              hipStream_t stream)
{
    const float* x  = (const float*)d_in[0];
    const float* cb = (const float*)d_in[1];
    float* out = (float*)d_out;
    float* ws  = (float*)d_ws;
    float* b2      = ws;                                   // [1024]
    float* avg_acc = ws + K;                               // [1024]
    float* scal    = ws + 2 * K;                           // [3]: mse, H, counter
    h8*    cfrag   = (h8*)((char*)d_ws + 16384);           // [4096*64] frags (512 KB)

    vq_prep<<<128, 256, 0, stream>>>(cb, b2, cfrag, avg_acc, scal);
    vq_mfma<<<NBLK, 512, 0, stream>>>(x, cb, cfrag, b2, avg_acc, scal, out);
}